// Round 1
// 314.970 us; speedup vs baseline: 1.6496x; 1.6496x over previous
//
#include <hip/hip_runtime.h>
#include <hip/hip_bf16.h>

// Problem constants (from reference): E=1e6 events, 3 nodes, MEM=4, RAW=2, TIME=4.
// Strategy:
//  1) Stable sort events by timestamp: bucket sort on t*2^20 (atomic scatter) +
//     per-bucket insertion-sort fixup keyed on (t_bits, idx)  == JAX stable argsort.
//  2) Chunked-speculative scan (GRU memory is contractive): one 4-LANE QUAD per
//     32-event chunk. Lane q owns memory component k=q of all 3 nodes; the
//     12x14 / 12x4 GRU matvecs are split 3-rows-per-lane; cross-lane gathers of
//     sm/dm/phi use DPP quad_perm (VALU, 1 cyc) with per-lane xor-permuted
//     weight columns (W[row][q^c]) so dot products sum correctly.
//     => 125k threads (1954 waves, ~2/SIMD on all 256 CUs) with NO extra
//     warmup work vs the serial-thread version.

#define NBUCK (1 << 20)
#define CHUNK 32
#define WARM  96

typedef unsigned int uint;

__device__ __forceinline__ int bucket_of(float t) {
    int b = (int)(t * 1048576.0f);
    if (b < 0) b = 0;
    if (b > NBUCK - 1) b = NBUCK - 1;
    return b;
}

// ---------------- sort kernels ----------------

__global__ void k_count(const float* __restrict__ ts, uint* __restrict__ cnt, int E) {
    int i = blockIdx.x * blockDim.x + threadIdx.x;
    if (i < E) {
        atomicAdd(&cnt[bucket_of(ts[i])], 1u);
    }
}

__global__ void k_block_sums(const uint* __restrict__ cnt, uint* __restrict__ sums) {
    __shared__ uint sd[256];
    int b = blockIdx.x, tid = threadIdx.x;
    const uint4* p = ((const uint4*)cnt) + (size_t)b * 256 + tid;
    uint4 v = *p;
    uint s = v.x + v.y + v.z + v.w;
    sd[tid] = s;
    __syncthreads();
    for (int off = 128; off > 0; off >>= 1) {
        if (tid < off) sd[tid] += sd[tid + off];
        __syncthreads();
    }
    if (tid == 0) sums[b] = sd[0];
}

__global__ void k_scan_sums(uint* __restrict__ sums) {
    __shared__ uint sd[1024];
    int tid = threadIdx.x;
    uint mine = sums[tid];
    sd[tid] = mine;
    __syncthreads();
    for (int off = 1; off < 1024; off <<= 1) {
        uint u = (tid >= off) ? sd[tid - off] : 0u;
        __syncthreads();
        sd[tid] += u;
        __syncthreads();
    }
    sums[tid] = sd[tid] - mine;  // exclusive
}

__global__ void k_scan_apply(uint* __restrict__ cnt, const uint* __restrict__ sums) {
    __shared__ uint sd[256];
    int b = blockIdx.x, tid = threadIdx.x;
    uint4* p = ((uint4*)cnt) + (size_t)b * 256 + tid;
    uint4 v = *p;
    uint tsum = v.x + v.y + v.z + v.w;
    sd[tid] = tsum;
    __syncthreads();
    for (int off = 1; off < 256; off <<= 1) {
        uint u = (tid >= off) ? sd[tid - off] : 0u;
        __syncthreads();
        sd[tid] += u;
        __syncthreads();
    }
    uint base = sums[b] + sd[tid] - tsum;  // exclusive for this thread's 4 elems
    uint4 o;
    o.x = base;
    o.y = base + v.x;
    o.z = o.y + v.y;
    o.w = o.z + v.z;
    *p = o;
}

__global__ void k_scatter(const int* __restrict__ src, const int* __restrict__ dst,
                          const float* __restrict__ ts, const float* __restrict__ ef,
                          uint* __restrict__ cnt, uint4* __restrict__ rec, int E) {
    int i = blockIdx.x * blockDim.x + threadIdx.x;
    if (i >= E) return;
    float t = ts[i];
    int b = bucket_of(t);
    uint pos = atomicAdd(&cnt[b], 1u);
    float2 f = ((const float2*)ef)[i];
    uint code = ((uint)src[i]) | (((uint)dst[i]) << 2) | (((uint)i) << 4);
    rec[pos] = make_uint4(code, __float_as_uint(t), __float_as_uint(f.x), __float_as_uint(f.y));
}

// After scatter, cnt[b] == inclusive prefix (start of bucket b+1). Sort each
// bucket's records by (t_bits asc, idx asc) => deterministic stable order.
__global__ void k_fixup(const uint* __restrict__ cnt, uint4* __restrict__ rec) {
    int b = blockIdx.x * blockDim.x + threadIdx.x;
    if (b >= NBUCK) return;
    uint beg = (b == 0) ? 0u : cnt[b - 1];
    uint end = cnt[b];
    if (end - beg < 2u) return;
    for (uint i = beg + 1; i < end; i++) {
        uint4 r = rec[i];
        uint ki = r.x >> 4;
        uint kt = r.y;  // positive float bits: monotonic as uint
        int j = (int)i - 1;
        while (j >= (int)beg) {
            uint4 q = rec[j];
            if (q.y > kt || (q.y == kt && (q.x >> 4) > ki)) {
                rec[j + 1] = q;
                j--;
            } else break;
        }
        rec[(uint)(j + 1)] = r;
    }
}

// ---------------- scan kernel ----------------

// quad_perm DPP: xor1 = [1,0,3,2] = 0xB1, xor2 = [2,3,0,1] = 0x4E,
// xor3 = [3,2,1,0] = 0x1B.  1-cycle VALU cross-lane, no LDS.
template <int CTRL>
__device__ __forceinline__ float qp(float x) {
    return __int_as_float(
        __builtin_amdgcn_mov_dpp(__float_as_int(x), CTRL, 0xF, 0xF, true));
}

__device__ __forceinline__ float sigm(float x) {
    // 1/(1+e^-x) via v_exp_f32 + v_rcp_f32 (~1ulp each): 4 instructions,
    // vs __frcp_rn's ~10-inst correctly-rounded div sequence.
    return __builtin_amdgcn_rcpf(1.0f + __builtin_amdgcn_exp2f(-1.442695041f * x));
}
__device__ __forceinline__ float tanh_fast(float x) {
    // tanh(x) = 1 - 2/(1+e^{2x})
    return fmaf(-2.0f,
                __builtin_amdgcn_rcpf(1.0f + __builtin_amdgcn_exp2f(2.885390082f * x)),
                1.0f);
}

__global__ void __launch_bounds__(256) k_scan(
    const uint4* __restrict__ rec,
    const float* __restrict__ Wlin, const float* __restrict__ blin,
    const float* __restrict__ Wtime, const float* __restrict__ btime,
    const float* __restrict__ Wih, const float* __restrict__ Whh,
    const float* __restrict__ bih, const float* __restrict__ bhh,
    float* __restrict__ out, int E, int nchunk) {
    // LDS weight cache: [0,168) Wih, [168,216) Whh, [216,228) bih, [228,240) bhh,
    // [240,260) Wlin, [260,262) blin, [262,266) w_t, [266,270) b_time
    __shared__ float sW[272];
    int tid = threadIdx.x;
    for (int i = tid; i < 270; i += 256) {
        float v;
        if (i < 168) v = Wih[i];
        else if (i < 216) v = Whh[i - 168];
        else if (i < 228) v = bih[i - 216];
        else if (i < 240) v = bhh[i - 228];
        else if (i < 260) v = Wlin[i - 240];
        else if (i < 262) v = blin[i - 260];
        else if (i < 266) v = Wtime[i - 262];
        else v = btime[i - 266];
        sW[i] = v;
    }
    __syncthreads();

    int g = blockIdx.x * 256 + tid;
    int quad = g >> 2;        // one chain (chunk) per 4-lane quad
    if (quad >= nchunk) return;
    int q = tid & 3;          // this lane owns memory component k=q

    // Per-lane weight preload, columns xor-permuted to match DPP gather order:
    // gathered vector element c holds component (q^c), so store W[row][q^c] at c.
    float A[3][4], Bw[3][4], Pw[3][4], Hw[3][4], Fw[3][2], bi[3], bh[3];
#pragma unroll
    for (int gate = 0; gate < 3; gate++) {   // rows q, 4+q, 8+q  (r, z, n)
        int row = gate * 4 + q;
#pragma unroll
        for (int c = 0; c < 4; c++) {
            int col = q ^ c;
            A[gate][c] = sW[row * 14 + col];        // x[0:4]  block
            Bw[gate][c] = sW[row * 14 + 4 + col];   // x[4:8]  block
            Pw[gate][c] = sW[row * 14 + 10 + col];  // x[10:14] block (phi)
            Hw[gate][c] = sW[168 + row * 4 + col];  // W_hh
        }
        Fw[gate][0] = sW[row * 14 + 8];
        Fw[gate][1] = sW[row * 14 + 9];
        bi[gate] = sW[216 + row];
        bh[gate] = sW[228 + row];
    }
    float wtq = sW[262 + q], btq = sW[266 + q];
    float wl0s = sW[240 + q], wl0d = sW[244 + q];
    float wl1s = sW[250 + q], wl1d = sW[254 + q];
    float wf00 = sW[248], wf01 = sW[249], wf10 = sW[258], wf11 = sW[259];
    float bl0 = sW[260], bl1 = sW[261];

    // own component of each node's memory; lu replicated across the quad
    float m0 = 0.f, m1 = 0.f, m2 = 0.f;
    float lu0 = 0.f, lu1 = 0.f, lu2 = 0.f;

    int emit0 = quad * CHUNK;
    int j0 = emit0 - WARM;
    if (j0 < 0) j0 = 0;
    int jend = emit0 + CHUNK;
    if (jend > E) jend = E;

    uint4 r = rec[j0];  // all 4 lanes of the quad load the same address
    for (int j = j0; j < jend; j++) {
        int jn = (j + 1 < jend) ? j + 1 : j;
        uint4 rn = rec[jn];  // state-independent prefetch of next record

        uint code = r.x;
        float t = __uint_as_float(r.y);
        float f0 = __uint_as_float(r.z);
        float f1 = __uint_as_float(r.w);
        int s = (int)(code & 3u);
        int d = (int)((code >> 2) & 3u);
        uint oi = code >> 4;

        float sm = (s == 0) ? m0 : ((s == 1) ? m1 : m2);
        float dm = (d == 0) ? m0 : ((d == 1) ? m1 : m2);
        float lus = (s == 0) ? lu0 : ((s == 1) ? lu1 : lu2);
        float lud = (d == 0) ? lu0 : ((d == 1) ? lu1 : lu2);
        float ps = __cosf(fmaf(wtq, t - lus, btq));
        float pd = __cosf(fmaf(wtq, t - lud, btq));

        if (j >= emit0) {
            // distributed logit: own-component partials, butterfly quad-reduce
            float p0 = fmaf(wl0s, sm, wl0d * dm);
            float p1 = fmaf(wl1s, sm, wl1d * dm);
            p0 += qp<0xB1>(p0);
            p0 += qp<0x4E>(p0);
            p1 += qp<0xB1>(p1);
            p1 += qp<0x4E>(p1);
            if (q == 0) {
                float l0 = fmaf(wf01, f1, fmaf(wf00, f0, p0 + bl0));
                float l1 = fmaf(wf11, f1, fmaf(wf10, f0, p1 + bl1));
                ((float2*)out)[oi] = make_float2(l0, l1);
            }
        }

        // quad all-gather (xor order: element c = component q^c)
        float smg[4] = {sm, qp<0xB1>(sm), qp<0x4E>(sm), qp<0x1B>(sm)};
        float dmg[4] = {dm, qp<0xB1>(dm), qp<0x4E>(dm), qp<0x1B>(dm)};
        float psg[4] = {ps, qp<0xB1>(ps), qp<0x4E>(ps), qp<0x1B>(ps)};
        float pdg[4] = {pd, qp<0xB1>(pd), qp<0x4E>(pd), qp<0x1B>(pd)};

        // 3 rows of each GRU's gx/gh per lane (rows q, 4+q, 8+q)
        float gxs[3], gxd[3], ghs[3], ghd[3];
#pragma unroll
        for (int gate = 0; gate < 3; gate++) {
            float base = fmaf(Fw[gate][0], f0, fmaf(Fw[gate][1], f1, bi[gate]));
            float as = base, ad = base;
            float hs = bh[gate], hd = bh[gate];
#pragma unroll
            for (int c = 0; c < 4; c++) {
                as = fmaf(A[gate][c], smg[c], as);
                as = fmaf(Bw[gate][c], dmg[c], as);
                as = fmaf(Pw[gate][c], psg[c], as);
                ad = fmaf(A[gate][c], dmg[c], ad);
                ad = fmaf(Bw[gate][c], smg[c], ad);
                ad = fmaf(Pw[gate][c], pdg[c], ad);
                hs = fmaf(Hw[gate][c], smg[c], hs);
                hd = fmaf(Hw[gate][c], dmg[c], hd);
            }
            gxs[gate] = as;
            gxd[gate] = ad;
            ghs[gate] = hs;
            ghd[gate] = hd;
        }

        float rs = sigm(gxs[0] + ghs[0]);
        float zs = sigm(gxs[1] + ghs[1]);
        float ns = tanh_fast(fmaf(rs, ghs[2], gxs[2]));
        float news = fmaf(zs, sm - ns, ns);  // (1-z)*n + z*h
        float rd = sigm(gxd[0] + ghd[0]);
        float zd = sigm(gxd[1] + ghd[1]);
        float nd = tanh_fast(fmaf(rd, ghd[2], gxd[2]));
        float newd = fmaf(zd, dm - nd, nd);

        bool s0 = (s == 0), s1 = (s == 1), s2 = (s == 2);
        bool d0 = (d == 0), d1 = (d == 1), d2 = (d == 2);
        m0 = d0 ? newd : (s0 ? news : m0);
        m1 = d1 ? newd : (s1 ? news : m1);
        m2 = d2 ? newd : (s2 ? news : m2);
        lu0 = (s0 || d0) ? t : lu0;
        lu1 = (s1 || d1) ? t : lu1;
        lu2 = (s2 || d2) ? t : lu2;

        r = rn;
    }
}

// ---------------- launcher ----------------

extern "C" void kernel_launch(void* const* d_in, const int* in_sizes, int n_in,
                              void* d_out, int out_size, void* d_ws, size_t ws_size,
                              hipStream_t stream) {
    const int* src = (const int*)d_in[0];
    const int* dst = (const int*)d_in[1];
    const float* ts = (const float*)d_in[2];
    const float* ef = (const float*)d_in[3];
    const float* Wlin = (const float*)d_in[4];
    const float* blin = (const float*)d_in[5];
    const float* Wtime = (const float*)d_in[6];
    const float* btime = (const float*)d_in[7];
    const float* Wih = (const float*)d_in[8];
    const float* Whh = (const float*)d_in[9];
    const float* bih = (const float*)d_in[10];
    const float* bhh = (const float*)d_in[11];
    float* out = (float*)d_out;
    int E = in_sizes[0];

    // workspace layout: rec[E] (16B each) | cnt[NBUCK] u32 | sums[1024] u32
    unsigned char* ws = (unsigned char*)d_ws;
    uint4* rec = (uint4*)ws;
    size_t off = ((size_t)E * 16 + 255) & ~(size_t)255;
    uint* cnt = (uint*)(ws + off);
    uint* sums = (uint*)(ws + off + (size_t)NBUCK * 4);

    hipMemsetAsync(cnt, 0, (size_t)NBUCK * sizeof(uint), stream);

    int tb = 256;
    int gE = (E + tb - 1) / tb;
    k_count<<<gE, tb, 0, stream>>>(ts, cnt, E);
    k_block_sums<<<NBUCK / 1024, 256, 0, stream>>>(cnt, sums);
    k_scan_sums<<<1, 1024, 0, stream>>>(sums);
    k_scan_apply<<<NBUCK / 1024, 256, 0, stream>>>(cnt, sums);
    k_scatter<<<gE, tb, 0, stream>>>(src, dst, ts, ef, cnt, rec, E);
    k_fixup<<<NBUCK / 256, 256, 0, stream>>>(cnt, rec);

    int nchunk = (E + CHUNK - 1) / CHUNK;
    int nthreads = nchunk * 4;  // 4 lanes per chain
    int gS = (nthreads + 255) / 256;
    k_scan<<<gS, 256, 0, stream>>>(rec, Wlin, blin, Wtime, btime, Wih, Whh, bih, bhh,
                                   out, E, nchunk);
}